// Round 13
// baseline (2294.414 us; speedup 1.0000x reference)
//
#include <hip/hip_runtime.h>

// InverseRecurrentLayer v13 — tag-in-data exchange (no per-step flags).
// Three dispatches (cvt_wr, h_prepass unchanged from r11). Scan: r11 geometry
// (32 blocks = 4 row-groups x 8 col-splits, 512 thr, wf[32] in regs), but the
// state exchange embeds a 1-bit generation tag in each 16B chunk (LSB of h[7],
// written by ONE dwordx4 -> no torn reads). Consumer stage-loads retry until
// tags match -> gate+stage merged into one MALL RT; per-step flag store, drain
// and end barrier deleted. One-time init gate (proven r11 flag pattern) kills
// cross-replay stale-slot0 acceptance; slot1 and later are tag/chain-protected.
// v12's XCD-local path abandoned (hang: unverifiable cross-L2 coherence).

#define TSTEPS 512

typedef __attribute__((ext_vector_type(4))) float f32x4;
typedef __attribute__((ext_vector_type(8))) _Float16 f16x8;
typedef unsigned long long u64;
typedef unsigned int u32;

union pk2 { _Float16 h[2]; u32 u; };
union chunk16 { f32x4 f; u32 d[4]; _Float16 h[8]; };

__device__ __forceinline__ f32x4 mfma16(f16x8 a, f16x8 b, f32x4 c){
  return __builtin_amdgcn_mfma_f32_16x16x32_f16(a, b, c, 0, 0, 0);
}
__device__ __forceinline__ void waitvm0(){ asm volatile("s_waitcnt vmcnt(0)" ::: "memory"); }
__device__ __forceinline__ f32x4 gload_sc1_b128(const void* p){
  f32x4 r; asm volatile("global_load_dwordx4 %0, %1, off sc1" : "=v"(r) : "v"(p) : "memory"); return r;
}
__device__ __forceinline__ void gstore_sc1_b128(void* p, f32x4 d){
  asm volatile("global_store_dwordx4 %0, %1, off sc1" :: "v"(p), "v"(d) : "memory");
}

// ---------------- (1) weight convert ----------------
__global__ void cvt_wr(const float* __restrict__ W, const float* __restrict__ R,
                       _Float16* __restrict__ Wa, _Float16* __restrict__ Wb,
                       _Float16* __restrict__ Rt){
  const int n  = gridDim.x * blockDim.x;
  const int id = blockIdx.x * blockDim.x + threadIdx.x;
  for (int i = id; i < 1024*1024; i += n){
    const float v = W[i];
    Wa[i] = (_Float16)v;                              // Wa[u][k] = W[u][k]  (W^T op)
    const int k = i >> 10, u = i & 1023;
    Wb[u*1024 + k] = (_Float16)v;                     // Wb[u][k] = W[k][u]  (W op)
  }
  for (int i = id; i < 512*1024; i += n){
    const int f = i >> 10, u = i & 1023;
    Rt[u*512 + f] = (_Float16)R[i];                   // Rt[u][f] = R[f][u]
  }
}

// ---------------- (2) h prepass ----------------
__global__ __launch_bounds__(512, 2) void h_prepass(
    const float* __restrict__ inputs, const _Float16* __restrict__ Rt,
    const float* __restrict__ bias, float* __restrict__ out){
  const int t  = blockIdx.x;
  const int w  = threadIdx.x >> 6, l = threadIdx.x & 63;
  const int lr = l & 15, lg = l >> 4;
  const int b0 = (w >> 1) * 16;
  const int c0 = (w & 1) * 512;

  f32x4 acc[32];
  #pragma unroll
  for (int n = 0; n < 32; ++n) acc[n] = (f32x4){0.f,0.f,0.f,0.f};

  for (int kc = 0; kc < 16; ++kc){
    const float* ip = inputs + (size_t)(b0 + lr)*262144 + (size_t)t*512 + kc*32 + lg*8;
    float4 xa = *(const float4*)ip, xb = *(const float4*)(ip + 4);
    f16x8 a;
    a[0]=(_Float16)xa.x; a[1]=(_Float16)xa.y; a[2]=(_Float16)xa.z; a[3]=(_Float16)xa.w;
    a[4]=(_Float16)xb.x; a[5]=(_Float16)xb.y; a[6]=(_Float16)xb.z; a[7]=(_Float16)xb.w;
    const _Float16* rp = Rt + (size_t)(c0 + lr)*512 + kc*32 + lg*8;
    #pragma unroll
    for (int n = 0; n < 32; ++n){
      f16x8 b = *(const f16x8*)(rp + (size_t)n*(16*512));
      acc[n] = mfma16(a, b, acc[n]);
    }
  }
  #pragma unroll
  for (int n = 0; n < 32; ++n){
    const int u = c0 + n*16 + lr;
    const float bu = bias[u];
    #pragma unroll
    for (int j = 0; j < 4; ++j)
      out[(size_t)t*65536 + (size_t)(b0 + lg*4 + j)*1024 + u] = acc[n][j] + bu;
  }
}

// ---------------- (3) scan ----------------
__global__ __launch_bounds__(512, 2) void irl_scan(
    const _Float16* __restrict__ Wa, const _Float16* __restrict__ Wb,
    const float* __restrict__ x0, float* __restrict__ out,
    unsigned short* __restrict__ st, unsigned* __restrict__ flags)
{
  __shared__ char alds[16 * 2048];     // row-group state [16 rows][1024 k], swizzled

  const int tid = threadIdx.x;
  const int w   = tid >> 6;            // wave = n-tile owner AND producer-w stager
  const int l   = tid & 63;
  const int lr  = l & 15;
  const int lg  = l >> 4;
  const int cblk = blockIdx.x & 7;     // col-split (producer id in group)
  const int grp  = blockIdx.x >> 3;    // row-group
  const int col0 = cblk << 7;          // 128 cols per block
  const int r0   = grp << 4;           // 16 rows per group
  const int u    = col0 + w*16 + lr;
  unsigned* myf  = flags + (((grp << 3) + cblk) << 4);

  // ---- state[0] <- x0 : tagged 16B chunks (tag for gen 0 = 1) ----
  if (tid < 256){
    const int row = tid >> 4, ch = tid & 15;
    chunk16 c;
    #pragma unroll
    for (int j = 0; j < 8; ++j) c.h[j] = (_Float16)x0[col0 + ch*8 + j];
    c.d[3] |= 0x10000u;                              // LSB of h[7] = tag 1
    gstore_sc1_b128((char*)st + (size_t)(r0 + row)*2048 + col0*2 + ch*16, c.f);
  }
  waitvm0();
  __syncthreads();
  if (tid == 0)
    __hip_atomic_store(myf, 1u, __ATOMIC_RELAXED, __HIP_MEMORY_SCOPE_AGENT);
  // one-time gate (proven r11 pattern): all 8 group members init'd.
  // Kills cross-replay stale-slot0 (its tag collides with gen-0 at t=0 only).
  if (tid < 64){
    const int src = (tid < 8) ? tid : 0;
    const unsigned* pf = flags + (((grp << 3) + src) << 4);
    for (;;){
      unsigned v = __hip_atomic_load(pf, __ATOMIC_RELAXED, __HIP_MEMORY_SCOPE_AGENT);
      if (__all((int)(v >= 1u))) break;
      __builtin_amdgcn_s_sleep(1);
    }
  }
  __syncthreads();

  unsigned cur = 0;
  int pp = -1;
  f16x8 wf[32];                        // current phase, full K=1024 (128 VGPR)
  for (int t = 0; t < TSTEPS; ++t){
    const int ph = (t >> 6) & 1;       // 1 -> W (Wb), 0 -> W^T (Wa)
    if (ph != pp){
      pp = ph;
      const _Float16* Wsel = ph ? Wb : Wa;
      #pragma unroll
      for (int i = 0; i < 32; ++i)
        wf[i] = *(const f16x8*)(Wsel + (size_t)u*1024 + i*32 + lg*8);
    }

    // h prefetch (own prepass slice; plain cached loads)
    float hv[4];
    #pragma unroll
    for (int j = 0; j < 4; ++j)
      hv[j] = out[(size_t)t*65536 + (size_t)(r0 + lg*4 + j)*1024 + u];

    // ---- tag-verified stage: gate and load merged (retry until gen t visible) ----
    const u32 tag_exp = (((u32)t >> 1) & 1u) ^ 1u;
    const char* base = (const char*)st + ((size_t)cur << 17)
                     + (size_t)r0*2048 + w*256 + lr*16;
    chunk16 q[4];
    for (;;){
      #pragma unroll
      for (int i = 0; i < 4; ++i)
        q[i].f = gload_sc1_b128(base + (size_t)(i*4 + lg)*2048);
      waitvm0();
      int ok = 1;
      #pragma unroll
      for (int i = 0; i < 4; ++i)
        ok &= (int)(((q[i].d[3] >> 16) & 1u) == tag_exp);
      if (__all(ok)) break;
      __builtin_amdgcn_s_sleep(1);
    }
    __syncthreads();                   // prev-step MFMA reads of alds complete
    #pragma unroll
    for (int i = 0; i < 4; ++i){
      const int row = i*4 + lg, c = w*256 + lr*16;
      *(f32x4*)(alds + row*2048 + (c ^ ((row & 7) << 4))) = q[i].f;
    }
    __syncthreads();

    // ---- recurrent GEMM: 32 MFMAs, 2 chains ----
    f32x4 ac0 = {0.f,0.f,0.f,0.f}, ac1 = ac0;
    #pragma unroll
    for (int i = 0; i < 32; i += 2){
      f16x8 a0 = *(const f16x8*)(alds + lr*2048 + ((i*64 + lg*16) ^ ((lr & 7) << 4)));
      f16x8 a1 = *(const f16x8*)(alds + lr*2048 + (((i+1)*64 + lg*16) ^ ((lr & 7) << 4)));
      ac0 = mfma16(a0, wf[i], ac0);
      ac1 = mfma16(a1, wf[i+1], ac1);
    }
    const f32x4 acc = ac0 + ac1;

    // ---- epilogue: tanh -> out; pack 8 cols/16B via 3 shfl levels; tagged store ----
    char* nbB = (char*)st + ((size_t)(cur ^ 1u) << 17);
    const u32 tag_nxt = (((u32)(t + 1) >> 1) & 1u) ^ 1u;
    #pragma unroll
    for (int j = 0; j < 4; ++j){
      const int row = lg*4 + j;
      const float v = tanhf(acc[j] + hv[j]);
      __builtin_nontemporal_store(v, out + (size_t)t*65536 + (size_t)(r0 + row)*1024 + u);
      pk2 me; me.h[0] = (_Float16)v; me.h[1] = (_Float16)0.f;
      const u32 two  = (me.u & 0xffffu) | ((u32)__shfl_xor((int)me.u, 1) << 16);
      const u32 lo4  = two, hi4 = (u32)__shfl_xor((int)two, 2);
      chunk16 cst;
      cst.d[0] = (lr & 2) ? hi4 : lo4;       // lane lr%4==0 has cols u..u+3 in (lo4,hi4)
      cst.d[1] = (lr & 2) ? lo4 : hi4;
      cst.d[0] = lo4; cst.d[1] = hi4;        // (lr%8==0 path only; others discarded)
      cst.d[2] = (u32)__shfl_xor((int)lo4, 4);
      cst.d[3] = (u32)__shfl_xor((int)hi4, 4);
      cst.d[3] = (cst.d[3] & ~0x10000u) | (tag_nxt << 16);
      if (!(lr & 7))
        gstore_sc1_b128(nbB + (size_t)(r0 + row)*2048 + (size_t)(u & ~7)*2, cst.f);
    }

    cur ^= 1u;
    // no drain, no flag, no end-of-step barrier: the tags are the signal.
  }
}

extern "C" void kernel_launch(void* const* d_in, const int* in_sizes, int n_in,
                              void* d_out, int out_size, void* d_ws, size_t ws_size,
                              hipStream_t stream){
  (void)in_sizes; (void)n_in; (void)out_size; (void)ws_size;
  const float* inputs = (const float*)d_in[0];   // [64,512,512] f32
  const float* R      = (const float*)d_in[1];   // [512,1024]  f32
  const float* W      = (const float*)d_in[2];   // [1024,1024] f32
  const float* bias   = (const float*)d_in[3];   // [1024]      f32
  const float* x0     = (const float*)d_in[4];   // [1024]      f32
  float* out = (float*)d_out;                    // [512,64,1024] f32 (h, then states)

  char* ws = (char*)d_ws;
  unsigned* flags     = (unsigned*)ws;                    // 4 KB (init gate only)
  unsigned short* st  = (unsigned short*)(ws + 4096);     // 2 x 64x1024 fp16 (256 KB)
  _Float16* Rt = (_Float16*)(ws + (512<<10));             // 1 MB  @ 0.5 MB
  _Float16* Wa = (_Float16*)(ws + (2u<<20));              // 2 MB  @ 2 MB
  _Float16* Wb = (_Float16*)(ws + (4u<<20));              // 2 MB  @ 4 MB

  hipMemsetAsync(flags, 0, 4096, stream);
  hipLaunchKernelGGL(cvt_wr,    dim3(1024), dim3(256), 0, stream, W, R, Wa, Wb, Rt);
  hipLaunchKernelGGL(h_prepass, dim3(512),  dim3(512), 0, stream, inputs, Rt, bias, out);
  hipLaunchKernelGGL(irl_scan,  dim3(32),   dim3(512), 0, stream, Wa, Wb, x0, out, st, flags);
}